// Round 1
// baseline (984.825 us; speedup 1.0000x reference)
//
#include <hip/hip_runtime.h>
#include <hip/hip_bf16.h>

// GCN 2-layer forward on MI355X.
// Math: out = A~ ( relu( A~ (x W1) + b1 ) W2 ) + b2  with A~ = D^-1/2 (A+I) D^-1/2.
// Trick 1: A~ (h W2) = (A~ h) W2  -> both aggregations are 16-wide (64B/edge).
// Trick 2: norm factoring: agg(d) = dinv[d] * ( p[d] + sum_e p[src_e] ), p = dinv*h.
// Trick 3: CSR via counting sort each call (no float atomics in aggregation).

#define GN 100000
#define GE 3200000
#define F_IN 512
#define HID 16
#define NCLS 40
#define NB1 391          // ceil(GN/256)

// ---------------- graph build ----------------

__global__ __launch_bounds__(256) void k_hist(const int* __restrict__ ei, int* __restrict__ deg) {
    int e = blockIdx.x * 256 + threadIdx.x;      // grid sized exactly GE/256
    atomicAdd(&deg[ei[GE + e]], 1);              // dst row of edge_index
}

__global__ __launch_bounds__(256) void k_scan1(const int* __restrict__ deg, int* __restrict__ blockSums) {
    int i = blockIdx.x * 256 + threadIdx.x;
    int v = (i < GN) ? deg[i] : 0;
    #pragma unroll
    for (int m = 32; m >= 1; m >>= 1) v += __shfl_down(v, m, 64);
    __shared__ int ws_[4];
    if ((threadIdx.x & 63) == 0) ws_[threadIdx.x >> 6] = v;
    __syncthreads();
    if (threadIdx.x == 0) blockSums[blockIdx.x] = ws_[0] + ws_[1] + ws_[2] + ws_[3];
}

__global__ __launch_bounds__(512) void k_scan2(const int* __restrict__ blockSums, int* __restrict__ blockOff) {
    __shared__ int s[512];
    int t = threadIdx.x;
    int v = (t < NB1) ? blockSums[t] : 0;
    s[t] = v;
    __syncthreads();
    for (int off = 1; off < 512; off <<= 1) {
        int add = (t >= off) ? s[t - off] : 0;
        __syncthreads();
        s[t] += add;
        __syncthreads();
    }
    if (t < NB1) blockOff[t] = s[t] - v;   // exclusive block offsets
}

__global__ __launch_bounds__(256) void k_scan3(const int* __restrict__ deg, const int* __restrict__ blockOff,
                                               int* __restrict__ row_start, int* __restrict__ cursor,
                                               float* __restrict__ dinv) {
    __shared__ int s[256];
    int t = threadIdx.x;
    int i = blockIdx.x * 256 + t;
    int d = (i < GN) ? deg[i] : 0;
    s[t] = d;
    __syncthreads();
    for (int off = 1; off < 256; off <<= 1) {
        int add = (t >= off) ? s[t - off] : 0;
        __syncthreads();
        s[t] += add;
        __syncthreads();
    }
    if (i < GN) {
        int excl = s[t] - d + blockOff[blockIdx.x];
        row_start[i] = excl;
        cursor[i]    = excl;
        dinv[i]      = rsqrtf((float)(d + 1));   // +1 self-loop; deg>=1 always
    }
    if (blockIdx.x == 0 && t == 0) row_start[GN] = GE;
}

__global__ __launch_bounds__(256) void k_fill(const int* __restrict__ ei, int* __restrict__ cursor,
                                              int* __restrict__ csr) {
    int e = blockIdx.x * 256 + threadIdx.x;
    int s = ei[e];
    int d = ei[GE + e];
    int slot = atomicAdd(&cursor[d], 1);
    csr[slot] = s;
}

// ---------------- layer 1 linear: hs1 = dinv * (x @ W1) ----------------
// 16 lanes per row; lane t covers k in {j*64 + t*4 .. +3}; coalesced float4 loads.
__global__ __launch_bounds__(256) void k_lin1(const float* __restrict__ x, const float* __restrict__ W1,
                                              const float* __restrict__ dinv, float* __restrict__ hs1) {
    __shared__ float w1t[HID * 516];             // transposed, pad 512->516 (2-way LDS = free)
    for (int i = threadIdx.x; i < F_IN * HID; i += 256) {
        int k = i >> 4, c = i & 15;
        w1t[c * 516 + k] = W1[i];
    }
    __syncthreads();
    const int g = threadIdx.x >> 4;              // row within batch (0..15)
    const int t = threadIdx.x & 15;              // k-slice lane
    for (int batch = blockIdx.x; batch < GN / 16; batch += gridDim.x) {
        const int row = batch * 16 + g;
        const float* xr = x + (size_t)row * F_IN;
        float acc[16];
        #pragma unroll
        for (int c = 0; c < 16; ++c) acc[c] = 0.f;
        #pragma unroll
        for (int j = 0; j < 8; ++j) {
            const int k = j * 64 + t * 4;
            float4 xv = *reinterpret_cast<const float4*>(xr + k);
            #pragma unroll
            for (int c = 0; c < 16; ++c) {
                float4 wv = *reinterpret_cast<const float4*>(&w1t[c * 516 + k]);
                acc[c] += xv.x * wv.x + xv.y * wv.y + xv.z * wv.z + xv.w * wv.w;
            }
        }
        // butterfly reduce across the 16-lane group
        #pragma unroll
        for (int m = 1; m < 16; m <<= 1) {
            #pragma unroll
            for (int c = 0; c < 16; ++c) acc[c] += __shfl_xor(acc[c], m, 64);
        }
        float v = acc[0];                         // lane t keeps column t (static-index select)
        #pragma unroll
        for (int c = 1; c < 16; ++c) if (t == c) v = acc[c];
        hs1[(size_t)row * HID + t] = dinv[row] * v;
    }
}

// ---------------- aggregation 1: p = dinv * relu( dinv*(hs1[d]+sum hs1[s]) + b1 ) ----------------
__global__ __launch_bounds__(256) void k_agg1(const float* __restrict__ hs1, const int* __restrict__ csr,
                                              const int* __restrict__ row_start, const float* __restrict__ dinv,
                                              const float* __restrict__ b1, float* __restrict__ p) {
    int d = blockIdx.x * 16 + (threadIdx.x >> 4);   // exact: 6250*16 = 100000
    int c = threadIdx.x & 15;
    float acc = hs1[(size_t)d * HID + c];           // self-loop term (already dinv[d]-scaled)
    int e0 = row_start[d], e1 = row_start[d + 1];
    for (int e = e0; e < e1; ++e) {
        int s = csr[e];
        acc += hs1[(size_t)s * HID + c];
    }
    float di = dinv[d];
    float v = fmaxf(di * acc + b1[c], 0.f);
    p[(size_t)d * HID + c] = di * v;                // pre-scale for layer-2 aggregation
}

// ---------------- aggregation 2: q = dinv * ( p[d] + sum p[s] ) ----------------
__global__ __launch_bounds__(256) void k_agg2(const float* __restrict__ p, const int* __restrict__ csr,
                                              const int* __restrict__ row_start, const float* __restrict__ dinv,
                                              float* __restrict__ q) {
    int d = blockIdx.x * 16 + (threadIdx.x >> 4);
    int c = threadIdx.x & 15;
    float acc = p[(size_t)d * HID + c];
    int e0 = row_start[d], e1 = row_start[d + 1];
    for (int e = e0; e < e1; ++e) {
        int s = csr[e];
        acc += p[(size_t)s * HID + c];
    }
    q[(size_t)d * HID + c] = dinv[d] * acc;
}

// ---------------- layer 2 linear: out = q @ W2 + b2 ----------------
// 8 lanes per node, each lane computes 5 of the 40 output columns.
__global__ __launch_bounds__(256) void k_lin2(const float* __restrict__ q, const float* __restrict__ W2,
                                              const float* __restrict__ b2, float* __restrict__ out) {
    __shared__ float w2[HID * NCLS];
    __shared__ float b2s[NCLS];
    for (int i = threadIdx.x; i < HID * NCLS; i += 256) w2[i] = W2[i];
    if (threadIdx.x < NCLS) b2s[threadIdx.x] = b2[threadIdx.x];
    __syncthreads();
    int node = blockIdx.x * 32 + (threadIdx.x >> 3);   // exact: 3125*32 = 100000
    int l = threadIdx.x & 7;
    const float* qr = q + (size_t)node * HID;
    float qv[16];
    #pragma unroll
    for (int j = 0; j < 4; ++j) {
        float4 v = *reinterpret_cast<const float4*>(qr + j * 4);
        qv[j * 4 + 0] = v.x; qv[j * 4 + 1] = v.y; qv[j * 4 + 2] = v.z; qv[j * 4 + 3] = v.w;
    }
    #pragma unroll
    for (int j = 0; j < 5; ++j) {
        int cc = l + 8 * j;
        float a = b2s[cc];
        #pragma unroll
        for (int k = 0; k < 16; ++k) a += qv[k] * w2[k * NCLS + cc];
        out[(size_t)node * NCLS + cc] = a;
    }
}

// ---------------- launch ----------------

extern "C" void kernel_launch(void* const* d_in, const int* in_sizes, int n_in,
                              void* d_out, int out_size, void* d_ws, size_t ws_size,
                              hipStream_t stream) {
    const float* x  = (const float*)d_in[0];
    const int*   ei = (const int*)d_in[1];
    const float* W1 = (const float*)d_in[2];
    const float* b1 = (const float*)d_in[3];
    const float* W2 = (const float*)d_in[4];
    const float* b2 = (const float*)d_in[5];
    float* out = (float*)d_out;

    // workspace layout (256B aligned)
    char* base = (char*)d_ws;
    size_t o = 0;
    auto alloc = [&](size_t bytes) { char* r = base + o; o = (o + bytes + 255) & ~(size_t)255; return r; };
    int*   deg       = (int*)  alloc((size_t)GN * 4);
    int*   cursor    = (int*)  alloc((size_t)GN * 4);
    int*   row_start = (int*)  alloc(((size_t)GN + 1) * 4);
    float* dinv      = (float*)alloc((size_t)GN * 4);
    int*   blockSums = (int*)  alloc((size_t)NB1 * 4);
    int*   blockOff  = (int*)  alloc((size_t)NB1 * 4);
    int*   csr       = (int*)  alloc((size_t)GE * 4);
    float* hs1       = (float*)alloc((size_t)GN * HID * 4);
    float* p         = (float*)alloc((size_t)GN * HID * 4);
    float* q         = (float*)alloc((size_t)GN * HID * 4);

    hipMemsetAsync(deg, 0, (size_t)GN * 4, stream);

    k_hist <<<GE / 256, 256, 0, stream>>>(ei, deg);
    k_scan1<<<NB1, 256, 0, stream>>>(deg, blockSums);
    k_scan2<<<1, 512, 0, stream>>>(blockSums, blockOff);
    k_scan3<<<NB1, 256, 0, stream>>>(deg, blockOff, row_start, cursor, dinv);
    k_fill <<<GE / 256, 256, 0, stream>>>(ei, cursor, csr);

    k_lin1 <<<2048, 256, 0, stream>>>(x, W1, dinv, hs1);
    k_agg1 <<<GN / 16, 256, 0, stream>>>(hs1, csr, row_start, dinv, b1, p);
    k_agg2 <<<GN / 16, 256, 0, stream>>>(p, csr, row_start, dinv, q);
    k_lin2 <<<GN / 32, 256, 0, stream>>>(q, W2, b2, out);
}

// Round 2
// 760.231 us; speedup vs baseline: 1.2954x; 1.2954x over previous
//
#include <hip/hip_runtime.h>
#include <hip/hip_bf16.h>

// GCN 2-layer forward on MI355X.
// Math: out = A~ ( relu( A~ (x W1) + b1 ) W2 ) + b2  with A~ = D^-1/2 (A+I) D^-1/2.
// Trick 1: A~ (h W2) = (A~ h) W2  -> both aggregations are 16-wide (64B/edge).
// Trick 2: norm factoring: agg(d) = dinv[d] * ( p[d] + sum_e p[src_e] ), p = dinv*h.
// Trick 3: two-level bucket sort (32 nodes/bucket) -> coalesced CSR writes,
//          no node-level global atomics. (R1: k_fill had 15x write amp, 275us)

#define GN 100000
#define GE 3200000
#define F_IN 512
#define HID 16
#define NCLS 40
#define NBUCK 3125       // GN/32 buckets, 32 nodes each
#define BSH 5            // dst >> 5 = bucket

// ---------------- graph build: two-level bucket sort ----------------

// bucket histogram via LDS (dst only)
__global__ __launch_bounds__(256) void k_bhist(const int* __restrict__ dst4, int* __restrict__ bcnt) {
    __shared__ int h[NBUCK];
    for (int i = threadIdx.x; i < NBUCK; i += 256) h[i] = 0;
    __syncthreads();
    const int nvec = GE / 4;
    for (int i = blockIdx.x * 256 + threadIdx.x; i < nvec; i += gridDim.x * 256) {
        int4 d = reinterpret_cast<const int4*>(dst4)[i];
        atomicAdd(&h[d.x >> BSH], 1);
        atomicAdd(&h[d.y >> BSH], 1);
        atomicAdd(&h[d.z >> BSH], 1);
        atomicAdd(&h[d.w >> BSH], 1);
    }
    __syncthreads();
    for (int i = threadIdx.x; i < NBUCK; i += 256) {
        int v = h[i];
        if (v) atomicAdd(&bcnt[i], v);
    }
}

// exclusive scan of 3125 bucket counts; writes bbase (and bcur copy)
__global__ __launch_bounds__(1024) void k_bscan(const int* __restrict__ bcnt, int* __restrict__ bbase,
                                                int* __restrict__ bcur) {
    __shared__ int s[1024];
    const int t = threadIdx.x;
    int v[4]; int sum = 0;
    #pragma unroll
    for (int j = 0; j < 4; ++j) {
        int idx = t * 4 + j;
        v[j] = (idx < NBUCK) ? bcnt[idx] : 0;
        sum += v[j];
    }
    s[t] = sum;
    __syncthreads();
    for (int off = 1; off < 1024; off <<= 1) {
        int add = (t >= off) ? s[t - off] : 0;
        __syncthreads();
        s[t] += add;
        __syncthreads();
    }
    int excl = s[t] - sum;
    #pragma unroll
    for (int j = 0; j < 4; ++j) {
        int idx = t * 4 + j;
        if (idx < NBUCK) { bbase[idx] = excl; bcur[idx] = excl; }
        excl += v[j];
    }
    if (t == 0) bbase[NBUCK] = GE;
}

// scatter packed (dst_low<<17 | src) into per-bucket contiguous regions
__global__ __launch_bounds__(256) void k_bscatter(const int* __restrict__ ei, int* __restrict__ bcur,
                                                  int* __restrict__ bdata) {
    int e = blockIdx.x * 256 + threadIdx.x;     // grid = GE/256 exactly
    int s = ei[e];
    int d = ei[GE + e];
    int b = d >> BSH;
    int slot = atomicAdd(&bcur[b], 1);
    bdata[slot] = ((d & 31) << 17) | s;
}

// per-bucket: count 32 nodes, prefix, emit row_start/dinv, rank-scatter coalesced csr
__global__ __launch_bounds__(256) void k_bsort(const int* __restrict__ bdata, const int* __restrict__ bbase,
                                               int* __restrict__ csr, int* __restrict__ row_start,
                                               float* __restrict__ dinv) {
    const int b = blockIdx.x;                    // 3125 blocks
    const int t = threadIdx.x;
    const int base = bbase[b];
    const int n = bbase[b + 1] - base;
    __shared__ int cnt[32], pref[32], cur[32];
    if (t < 32) cnt[t] = 0;
    __syncthreads();
    for (int i = t; i < n; i += 256) atomicAdd(&cnt[bdata[base + i] >> 17], 1);
    __syncthreads();
    if (t == 0) {
        int s = 0;
        #pragma unroll
        for (int j = 0; j < 32; ++j) { pref[j] = s; s += cnt[j]; }
    }
    __syncthreads();
    if (t < 32) {
        int node = b * 32 + t;
        row_start[node] = base + pref[t];
        dinv[node] = rsqrtf((float)(cnt[t] + 1));
        cur[t] = 0;
    }
    __syncthreads();
    for (int i = t; i < n; i += 256) {
        int pk = bdata[base + i];
        int dl = pk >> 17;
        int slot = atomicAdd(&cur[dl], 1);
        csr[base + pref[dl] + slot] = pk & 0x1FFFF;
    }
    if (b == 0 && t == 0) row_start[GN] = GE;
}

// ---------------- layer 1 linear: hs1 = dinv * (x @ W1) ----------------
// 16 lanes per row; coalesced float4 loads; 15-shfl tree reduce.
__global__ __launch_bounds__(256) void k_lin1(const float* __restrict__ x, const float* __restrict__ W1,
                                              const float* __restrict__ dinv, float* __restrict__ hs1) {
    __shared__ float w1t[HID * 516];             // transposed, pad 512->516 (2-way LDS = free)
    for (int i = threadIdx.x; i < F_IN * HID; i += 256) {
        int k = i >> 4, c = i & 15;
        w1t[c * 516 + k] = W1[i];
    }
    __syncthreads();
    const int g = threadIdx.x >> 4;              // row within batch (0..15)
    const int t = threadIdx.x & 15;              // k-slice lane
    for (int batch = blockIdx.x; batch < GN / 16; batch += gridDim.x) {
        const int row = batch * 16 + g;
        const float* xr = x + (size_t)row * F_IN;
        float acc[16];
        #pragma unroll
        for (int c = 0; c < 16; ++c) acc[c] = 0.f;
        #pragma unroll
        for (int j = 0; j < 8; ++j) {
            const int k = j * 64 + t * 4;
            float4 xv = *reinterpret_cast<const float4*>(xr + k);
            #pragma unroll
            for (int c = 0; c < 16; ++c) {
                float4 wv = *reinterpret_cast<const float4*>(&w1t[c * 516 + k]);
                acc[c] += xv.x * wv.x + xv.y * wv.y + xv.z * wv.z + xv.w * wv.w;
            }
        }
        // tree reduce: stage m halves values/lane; final lane t holds column t sum
        #pragma unroll
        for (int m = 1, nv = 16; m < 16; m <<= 1, nv >>= 1) {
            #pragma unroll
            for (int j = 0; j < 8; ++j) {
                if (j < nv / 2) {
                    float a = acc[2 * j], bb = acc[2 * j + 1];
                    bool hi = (t & m);
                    float mine  = hi ? bb : a;
                    float other = hi ? a : bb;
                    acc[j] = mine + __shfl_xor(other, m, 64);
                }
            }
        }
        hs1[(size_t)row * HID + t] = dinv[row] * acc[0];
    }
}

// ---------------- aggregation 1: p = dinv * relu( dinv*(hs1[d]+sum hs1[s]) + b1 ) ----------------
__global__ __launch_bounds__(256) void k_agg1(const float* __restrict__ hs1, const int* __restrict__ csr,
                                              const int* __restrict__ row_start, const float* __restrict__ dinv,
                                              const float* __restrict__ b1, float* __restrict__ p) {
    int d = blockIdx.x * 16 + (threadIdx.x >> 4);   // exact: 6250*16 = 100000
    int c = threadIdx.x & 15;
    float acc = hs1[(size_t)d * HID + c];           // self-loop term (already dinv[d]-scaled)
    int e0 = row_start[d], e1 = row_start[d + 1];
    int e = e0;
    for (; e + 4 <= e1; e += 4) {                   // unroll x4 for MLP
        int s0 = csr[e], s1 = csr[e + 1], s2 = csr[e + 2], s3 = csr[e + 3];
        float v0 = hs1[(size_t)s0 * HID + c];
        float v1 = hs1[(size_t)s1 * HID + c];
        float v2 = hs1[(size_t)s2 * HID + c];
        float v3 = hs1[(size_t)s3 * HID + c];
        acc += (v0 + v1) + (v2 + v3);
    }
    for (; e < e1; ++e) acc += hs1[(size_t)csr[e] * HID + c];
    float di = dinv[d];
    float v = fmaxf(di * acc + b1[c], 0.f);
    p[(size_t)d * HID + c] = di * v;                // pre-scale for layer-2 aggregation
}

// ---------------- aggregation 2: q = dinv * ( p[d] + sum p[s] ) ----------------
__global__ __launch_bounds__(256) void k_agg2(const float* __restrict__ p, const int* __restrict__ csr,
                                              const int* __restrict__ row_start, const float* __restrict__ dinv,
                                              float* __restrict__ q) {
    int d = blockIdx.x * 16 + (threadIdx.x >> 4);
    int c = threadIdx.x & 15;
    float acc = p[(size_t)d * HID + c];
    int e0 = row_start[d], e1 = row_start[d + 1];
    int e = e0;
    for (; e + 4 <= e1; e += 4) {
        int s0 = csr[e], s1 = csr[e + 1], s2 = csr[e + 2], s3 = csr[e + 3];
        float v0 = p[(size_t)s0 * HID + c];
        float v1 = p[(size_t)s1 * HID + c];
        float v2 = p[(size_t)s2 * HID + c];
        float v3 = p[(size_t)s3 * HID + c];
        acc += (v0 + v1) + (v2 + v3);
    }
    for (; e < e1; ++e) acc += p[(size_t)csr[e] * HID + c];
    q[(size_t)d * HID + c] = dinv[d] * acc;
}

// ---------------- layer 2 linear: out = q @ W2 + b2 ----------------
__global__ __launch_bounds__(256) void k_lin2(const float* __restrict__ q, const float* __restrict__ W2,
                                              const float* __restrict__ b2, float* __restrict__ out) {
    __shared__ float w2[HID * NCLS];
    __shared__ float b2s[NCLS];
    for (int i = threadIdx.x; i < HID * NCLS; i += 256) w2[i] = W2[i];
    if (threadIdx.x < NCLS) b2s[threadIdx.x] = b2[threadIdx.x];
    __syncthreads();
    int node = blockIdx.x * 32 + (threadIdx.x >> 3);   // exact: 3125*32 = 100000
    int l = threadIdx.x & 7;
    const float* qr = q + (size_t)node * HID;
    float qv[16];
    #pragma unroll
    for (int j = 0; j < 4; ++j) {
        float4 v = *reinterpret_cast<const float4*>(qr + j * 4);
        qv[j * 4 + 0] = v.x; qv[j * 4 + 1] = v.y; qv[j * 4 + 2] = v.z; qv[j * 4 + 3] = v.w;
    }
    #pragma unroll
    for (int j = 0; j < 5; ++j) {
        int cc = l + 8 * j;
        float a = b2s[cc];
        #pragma unroll
        for (int k = 0; k < 16; ++k) a += qv[k] * w2[k * NCLS + cc];
        out[(size_t)node * NCLS + cc] = a;
    }
}

// ---------------- launch ----------------

extern "C" void kernel_launch(void* const* d_in, const int* in_sizes, int n_in,
                              void* d_out, int out_size, void* d_ws, size_t ws_size,
                              hipStream_t stream) {
    const float* x  = (const float*)d_in[0];
    const int*   ei = (const int*)d_in[1];
    const float* W1 = (const float*)d_in[2];
    const float* b1 = (const float*)d_in[3];
    const float* W2 = (const float*)d_in[4];
    const float* b2 = (const float*)d_in[5];
    float* out = (float*)d_out;

    // workspace layout (256B aligned)
    char* base = (char*)d_ws;
    size_t o = 0;
    auto alloc = [&](size_t bytes) { char* r = base + o; o = (o + bytes + 255) & ~(size_t)255; return r; };
    int*   bcnt      = (int*)  alloc((size_t)NBUCK * 4);
    int*   bbase     = (int*)  alloc(((size_t)NBUCK + 1) * 4);
    int*   bcur      = (int*)  alloc((size_t)NBUCK * 4);
    int*   bdata     = (int*)  alloc((size_t)GE * 4);
    int*   csr       = (int*)  alloc((size_t)GE * 4);
    int*   row_start = (int*)  alloc(((size_t)GN + 1) * 4);
    float* dinv      = (float*)alloc((size_t)GN * 4);
    float* hs1       = (float*)alloc((size_t)GN * HID * 4);
    float* p         = (float*)alloc((size_t)GN * HID * 4);
    float* q         = (float*)alloc((size_t)GN * HID * 4);

    hipMemsetAsync(bcnt, 0, (size_t)NBUCK * 4, stream);

    k_bhist   <<<512, 256, 0, stream>>>(ei + GE, bcnt);
    k_bscan   <<<1, 1024, 0, stream>>>(bcnt, bbase, bcur);
    k_bscatter<<<GE / 256, 256, 0, stream>>>(ei, bcur, bdata);
    k_bsort   <<<NBUCK, 256, 0, stream>>>(bdata, bbase, csr, row_start, dinv);

    k_lin1 <<<2048, 256, 0, stream>>>(x, W1, dinv, hs1);
    k_agg1 <<<GN / 16, 256, 0, stream>>>(hs1, csr, row_start, dinv, b1, p);
    k_agg2 <<<GN / 16, 256, 0, stream>>>(p, csr, row_start, dinv, q);
    k_lin2 <<<GN / 32, 256, 0, stream>>>(q, W2, b2, out);
}

// Round 4
// 674.742 us; speedup vs baseline: 1.4596x; 1.1267x over previous
//
#include <hip/hip_runtime.h>
#include <hip/hip_bf16.h>

// GCN 2-layer forward on MI355X.
// Math: out = A~ ( relu( A~ (x W1) + b1 ) W2 ) + b2  with A~ = D^-1/2 (A+I) D^-1/2.
// Trick 1: A~ (h W2) = (A~ h) W2  -> both aggregations are 16-wide (64B/edge).
// Trick 2: norm factoring: agg(d) = dinv[d] * ( p[d] + sum_e p[src_e] ), p = dinv*h.
// Trick 3: bucket sort with XCD-PARTITIONED sub-buckets: every 64B line of a
//          (bucket,partition) window is written by one XCD only -> lines fill in
//          that XCD's L2 before writeback. (R2: mixed-XCD windows gave 12.5x write amp.)

#define GN 100000
#define GE 3200000
#define F_IN 512
#define HID 16
#define NCLS 40
#define NBUCK 3125       // GN/32 buckets, 32 nodes each
#define NB8 (NBUCK * 8)  // (bucket, xcd-partition) cells
#define BSH 5            // dst >> 5 = bucket
#define NCHUNK 3125      // GE/1024 edge chunks; chunk c -> partition c&7

// ---------------- graph build ----------------

// histogram into (bucket, partition) cells. Block i handles chunks i, i+256, ...
// (256 % 8 == 0 so chunk&7 == blockIdx&7 is constant per block).
__global__ __launch_bounds__(256) void k_bhist(const int* __restrict__ dst, int* __restrict__ bcnt) {
    __shared__ int h[NBUCK];
    for (int i = threadIdx.x; i < NBUCK; i += 256) h[i] = 0;
    __syncthreads();
    for (int c = blockIdx.x; c < NCHUNK; c += 256) {
        int4 d = reinterpret_cast<const int4*>(dst)[c * 256 + threadIdx.x];
        atomicAdd(&h[d.x >> BSH], 1);
        atomicAdd(&h[d.y >> BSH], 1);
        atomicAdd(&h[d.z >> BSH], 1);
        atomicAdd(&h[d.w >> BSH], 1);
    }
    __syncthreads();
    const int x = blockIdx.x & 7;
    for (int i = threadIdx.x; i < NBUCK; i += 256) {
        int v = h[i];
        if (v) atomicAdd(&bcnt[i * 8 + x], v);
    }
}

// exclusive scan of 25000 cells; single block, 25 cells/thread
__global__ __launch_bounds__(1024) void k_bscan(const int* __restrict__ bcnt, int* __restrict__ bbase,
                                                int* __restrict__ bcur) {
    __shared__ int s[1024];
    const int t = threadIdx.x;
    int v[25]; int sum = 0;
    #pragma unroll
    for (int j = 0; j < 25; ++j) {
        int idx = t * 25 + j;
        int val = (idx < NB8) ? bcnt[idx] : 0;
        v[j] = val; sum += val;
    }
    s[t] = sum;
    __syncthreads();
    for (int off = 1; off < 1024; off <<= 1) {
        int add = (t >= off) ? s[t - off] : 0;
        __syncthreads();
        s[t] += add;
        __syncthreads();
    }
    int excl = s[t] - sum;
    #pragma unroll
    for (int j = 0; j < 25; ++j) {
        int idx = t * 25 + j;
        if (idx < NB8) { bbase[idx] = excl; bcur[idx] = excl; }
        excl += v[j];
    }
    if (t == 1023) bbase[NB8] = GE;
}

// scatter packed (dst_low<<17 | src) into (bucket, blockIdx&7) windows
__global__ __launch_bounds__(256) void k_bscatter(const int* __restrict__ ei, int* __restrict__ bcur,
                                                  int* __restrict__ bdata) {
    const int c = blockIdx.x;                 // chunk == block; grid = NCHUNK
    const int x = c & 7;
    const int idx = c * 256 + threadIdx.x;    // int4 index
    int4 s4 = reinterpret_cast<const int4*>(ei)[idx];
    int4 d4 = reinterpret_cast<const int4*>(ei + GE)[idx];
    int b, slot;
    b = d4.x >> BSH; slot = atomicAdd(&bcur[b * 8 + x], 1); bdata[slot] = ((d4.x & 31) << 17) | s4.x;
    b = d4.y >> BSH; slot = atomicAdd(&bcur[b * 8 + x], 1); bdata[slot] = ((d4.y & 31) << 17) | s4.y;
    b = d4.z >> BSH; slot = atomicAdd(&bcur[b * 8 + x], 1); bdata[slot] = ((d4.z & 31) << 17) | s4.z;
    b = d4.w >> BSH; slot = atomicAdd(&bcur[b * 8 + x], 1); bdata[slot] = ((d4.w & 31) << 17) | s4.w;
}

// per-bucket: count 32 nodes, prefix, emit row_start/dinv, rank-scatter coalesced csr
__global__ __launch_bounds__(256) void k_bsort(const int* __restrict__ bdata, const int* __restrict__ bbase,
                                               int* __restrict__ csr, int* __restrict__ row_start,
                                               float* __restrict__ dinv) {
    const int b = blockIdx.x;                    // NBUCK blocks
    const int t = threadIdx.x;
    const int base = bbase[b * 8];
    const int n = bbase[(b + 1) * 8] - base;
    __shared__ int cnt[32], pref[32], cur[32];
    if (t < 32) cnt[t] = 0;
    __syncthreads();
    for (int i = t; i < n; i += 256) atomicAdd(&cnt[bdata[base + i] >> 17], 1);
    __syncthreads();
    if (t == 0) {
        int s = 0;
        #pragma unroll
        for (int j = 0; j < 32; ++j) { pref[j] = s; s += cnt[j]; }
    }
    __syncthreads();
    if (t < 32) {
        int node = b * 32 + t;
        row_start[node] = base + pref[t];
        dinv[node] = rsqrtf((float)(cnt[t] + 1));
        cur[t] = 0;
    }
    __syncthreads();
    for (int i = t; i < n; i += 256) {
        int pk = bdata[base + i];
        int dl = pk >> 17;
        int slot = atomicAdd(&cur[dl], 1);
        csr[base + pref[dl] + slot] = pk & 0x1FFFF;
    }
    if (b == 0 && t == 0) row_start[GN] = GE;
}

// ---------------- layer 1 linear: hs1 = dinv * (x @ W1) ----------------
__global__ __launch_bounds__(256) void k_lin1(const float* __restrict__ x, const float* __restrict__ W1,
                                              const float* __restrict__ dinv, float* __restrict__ hs1) {
    __shared__ float w1t[HID * 516];             // transposed, pad 512->516 (2-way LDS = free)
    for (int i = threadIdx.x; i < F_IN * HID; i += 256) {
        int k = i >> 4, c = i & 15;
        w1t[c * 516 + k] = W1[i];
    }
    __syncthreads();
    const int g = threadIdx.x >> 4;              // row within batch (0..15)
    const int t = threadIdx.x & 15;              // k-slice lane
    for (int batch = blockIdx.x; batch < GN / 16; batch += gridDim.x) {
        const int row = batch * 16 + g;
        const float* xr = x + (size_t)row * F_IN;
        float acc[16];
        #pragma unroll
        for (int c = 0; c < 16; ++c) acc[c] = 0.f;
        #pragma unroll
        for (int j = 0; j < 8; ++j) {
            const int k = j * 64 + t * 4;
            float4 xv = *reinterpret_cast<const float4*>(xr + k);
            #pragma unroll
            for (int c = 0; c < 16; ++c) {
                float4 wv = *reinterpret_cast<const float4*>(&w1t[c * 516 + k]);
                acc[c] += xv.x * wv.x + xv.y * wv.y + xv.z * wv.z + xv.w * wv.w;
            }
        }
        #pragma unroll
        for (int m = 1, nv = 16; m < 16; m <<= 1, nv >>= 1) {
            #pragma unroll
            for (int j = 0; j < 8; ++j) {
                if (j < nv / 2) {
                    float a = acc[2 * j], bb = acc[2 * j + 1];
                    bool hi = (t & m);
                    float mine  = hi ? bb : a;
                    float other = hi ? a : bb;
                    acc[j] = mine + __shfl_xor(other, m, 64);
                }
            }
        }
        hs1[(size_t)row * HID + t] = dinv[row] * acc[0];
    }
}

// ---------------- aggregation 1: p = dinv * relu( dinv*(hs1[d]+sum hs1[s]) + b1 ) ----------------
__global__ __launch_bounds__(256) void k_agg1(const float* __restrict__ hs1, const int* __restrict__ csr,
                                              const int* __restrict__ row_start, const float* __restrict__ dinv,
                                              const float* __restrict__ b1, float* __restrict__ p) {
    int d = blockIdx.x * 16 + (threadIdx.x >> 4);   // exact: 6250*16 = 100000
    int c = threadIdx.x & 15;
    float acc = hs1[(size_t)d * HID + c];           // self-loop (already dinv[d]-scaled)
    int e0 = row_start[d], e1 = row_start[d + 1];
    int e = e0;
    for (; e + 8 <= e1; e += 8) {
        float v0 = hs1[(size_t)csr[e + 0] * HID + c];
        float v1 = hs1[(size_t)csr[e + 1] * HID + c];
        float v2 = hs1[(size_t)csr[e + 2] * HID + c];
        float v3 = hs1[(size_t)csr[e + 3] * HID + c];
        float v4 = hs1[(size_t)csr[e + 4] * HID + c];
        float v5 = hs1[(size_t)csr[e + 5] * HID + c];
        float v6 = hs1[(size_t)csr[e + 6] * HID + c];
        float v7 = hs1[(size_t)csr[e + 7] * HID + c];
        acc += ((v0 + v1) + (v2 + v3)) + ((v4 + v5) + (v6 + v7));
    }
    for (; e < e1; ++e) acc += hs1[(size_t)csr[e] * HID + c];
    float di = dinv[d];
    float v = fmaxf(di * acc + b1[c], 0.f);
    p[(size_t)d * HID + c] = di * v;                // pre-scale for layer-2 aggregation
}

// ---------------- agg2 + lin2 fused: out = (dinv*(p[d]+sum p[s])) @ W2 + b2 ----------------
__global__ __launch_bounds__(256) void k_agg2lin2(const float* __restrict__ p, const int* __restrict__ csr,
                                                  const int* __restrict__ row_start, const float* __restrict__ dinv,
                                                  const float* __restrict__ W2, const float* __restrict__ b2,
                                                  float* __restrict__ out) {
    __shared__ float w2[HID * NCLS];
    __shared__ float b2s[NCLS];
    __shared__ float qs[16][17];
    for (int i = threadIdx.x; i < HID * NCLS; i += 256) w2[i] = W2[i];
    if (threadIdx.x < NCLS) b2s[threadIdx.x] = b2[threadIdx.x];
    const int g = threadIdx.x >> 4;
    const int c = threadIdx.x & 15;
    const int d = blockIdx.x * 16 + g;
    float acc = p[(size_t)d * HID + c];
    int e0 = row_start[d], e1 = row_start[d + 1];
    int e = e0;
    for (; e + 8 <= e1; e += 8) {
        float v0 = p[(size_t)csr[e + 0] * HID + c];
        float v1 = p[(size_t)csr[e + 1] * HID + c];
        float v2 = p[(size_t)csr[e + 2] * HID + c];
        float v3 = p[(size_t)csr[e + 3] * HID + c];
        float v4 = p[(size_t)csr[e + 4] * HID + c];
        float v5 = p[(size_t)csr[e + 5] * HID + c];
        float v6 = p[(size_t)csr[e + 6] * HID + c];
        float v7 = p[(size_t)csr[e + 7] * HID + c];
        acc += ((v0 + v1) + (v2 + v3)) + ((v4 + v5) + (v6 + v7));
    }
    for (; e < e1; ++e) acc += p[(size_t)csr[e] * HID + c];
    qs[g][c] = dinv[d] * acc;
    __syncthreads();
    // lin2: lane c -> columns c, c+16, (c<8: c+32)
    float a0 = b2s[c], a1 = b2s[c + 16], a2 = (c < 8) ? b2s[c + 32] : 0.f;
    #pragma unroll
    for (int k = 0; k < 16; ++k) {
        float qk = qs[g][k];
        a0 += qk * w2[k * NCLS + c];
        a1 += qk * w2[k * NCLS + c + 16];
        if (c < 8) a2 += qk * w2[k * NCLS + c + 32];
    }
    float* orow = out + (size_t)d * NCLS;
    orow[c] = a0;
    orow[c + 16] = a1;
    if (c < 8) orow[c + 32] = a2;
}

// ---------------- launch ----------------

extern "C" void kernel_launch(void* const* d_in, const int* in_sizes, int n_in,
                              void* d_out, int out_size, void* d_ws, size_t ws_size,
                              hipStream_t stream) {
    const float* x  = (const float*)d_in[0];
    const int*   ei = (const int*)d_in[1];
    const float* W1 = (const float*)d_in[2];
    const float* b1 = (const float*)d_in[3];
    const float* W2 = (const float*)d_in[4];
    const float* b2 = (const float*)d_in[5];
    float* out = (float*)d_out;

    char* base = (char*)d_ws;
    size_t o = 0;
    auto alloc = [&](size_t bytes) { char* r = base + o; o = (o + bytes + 255) & ~(size_t)255; return r; };
    int*   bcnt      = (int*)  alloc((size_t)NB8 * 4);
    int*   bbase     = (int*)  alloc(((size_t)NB8 + 1) * 4);
    int*   bcur      = (int*)  alloc((size_t)NB8 * 4);
    int*   bdata     = (int*)  alloc((size_t)GE * 4);
    int*   csr       = (int*)  alloc((size_t)GE * 4);
    int*   row_start = (int*)  alloc(((size_t)GN + 1) * 4);
    float* dinv      = (float*)alloc((size_t)GN * 4);
    float* hs1       = (float*)alloc((size_t)GN * HID * 4);
    float* p         = (float*)alloc((size_t)GN * HID * 4);

    hipMemsetAsync(bcnt, 0, (size_t)NB8 * 4, stream);

    k_bhist   <<<256, 256, 0, stream>>>(ei + GE, bcnt);
    k_bscan   <<<1, 1024, 0, stream>>>(bcnt, bbase, bcur);
    k_bscatter<<<NCHUNK, 256, 0, stream>>>(ei, bcur, bdata);
    k_bsort   <<<NBUCK, 256, 0, stream>>>(bdata, bbase, csr, row_start, dinv);

    k_lin1    <<<2048, 256, 0, stream>>>(x, W1, dinv, hs1);
    k_agg1    <<<GN / 16, 256, 0, stream>>>(hs1, csr, row_start, dinv, b1, p);
    k_agg2lin2<<<GN / 16, 256, 0, stream>>>(p, csr, row_start, dinv, W2, b2, out);
}

// Round 5
// 534.685 us; speedup vs baseline: 1.8419x; 1.2619x over previous
//
#include <hip/hip_runtime.h>
#include <hip/hip_bf16.h>

// GCN 2-layer forward on MI355X.
// Math: out = A~ ( relu( A~ (x W1) + b1 ) W2 ) + b2  with A~ = D^-1/2 (A+I) D^-1/2.
// Trick 1: A~ (h W2) = (A~ h) W2  -> both aggregations are 16-wide (64B/edge).
// Trick 2: norm factoring: agg(d) = dinv[d] * ( p[d] + sum_e p[src_e] ), p = dinv*h.
// Trick 3 (R5): two-pass radix build. Pass A: per-block run reservation into 196
//   super-buckets (block-owned contiguous runs -> ~2 writers/line max, vs 16 random
//   XCDs in R2-R4 which gave 9-12x write amp). Pass B: block-private 64KB window
//   counting sort -> final CSR, zero cross-block line sharing.

#define GN 100000
#define GE 3200000
#define F_IN 512
#define HID 16
#define NCLS 40
#define NSB 196          // super-buckets of 512 nodes; sb = dst >> 9
#define NSCB 782         // ceil(GE / 4096) scatter blocks (last block: 1024 edges)
#define NI4 800000       // GE / 4 int4 elements

// ---------------- pass A0: super-bucket histogram ----------------
__global__ __launch_bounds__(256) void k_sbhist(const int* __restrict__ dst, int* __restrict__ sbcnt) {
    __shared__ int h[NSB];
    const int t = threadIdx.x;
    if (t < NSB) h[t] = 0;
    __syncthreads();
    for (int i = blockIdx.x * 256 + t; i < NI4; i += gridDim.x * 256) {
        int4 d = reinterpret_cast<const int4*>(dst)[i];
        atomicAdd(&h[d.x >> 9], 1);
        atomicAdd(&h[d.y >> 9], 1);
        atomicAdd(&h[d.z >> 9], 1);
        atomicAdd(&h[d.w >> 9], 1);
    }
    __syncthreads();
    if (t < NSB && h[t]) atomicAdd(&sbcnt[t], h[t]);
}

// ---------------- pass A1: scan 196 counts -> bases ----------------
__global__ __launch_bounds__(256) void k_sbscan(const int* __restrict__ sbcnt, int* __restrict__ sbbase,
                                                int* __restrict__ sbcur) {
    __shared__ int s[256];
    const int t = threadIdx.x;
    int v = (t < NSB) ? sbcnt[t] : 0;
    s[t] = v;
    __syncthreads();
    for (int off = 1; off < 256; off <<= 1) {
        int add = (t >= off) ? s[t - off] : 0;
        __syncthreads();
        s[t] += add;
        __syncthreads();
    }
    if (t < NSB) { sbbase[t] = s[t] - v; sbcur[t] = s[t] - v; }
    if (t == 0) sbbase[NSB] = GE;
}

// ---------------- pass A2: block-run scatter into super-buckets ----------------
// Block c handles edges [c*4096, c*4096+4096). Per super-bucket: count in LDS,
// reserve ONE contiguous global run per (block, sb), then write. Lines of gdata
// are shared only at run boundaries (~2 blocks max).
__global__ __launch_bounds__(256) void k_scat(const int* __restrict__ ei, int* __restrict__ sbcur,
                                              int* __restrict__ gdata) {
    __shared__ int cnt[NSB], gb[NSB], cur[NSB];
    const int t = threadIdx.x;
    if (t < NSB) { cnt[t] = 0; cur[t] = 0; }
    __syncthreads();
    int4 sv[4], dv[4];
    bool ok[4];
    #pragma unroll
    for (int j = 0; j < 4; ++j) {
        int idx = blockIdx.x * 1024 + j * 256 + t;      // int4 index
        ok[j] = (idx < NI4);
        if (ok[j]) {
            sv[j] = reinterpret_cast<const int4*>(ei)[idx];
            dv[j] = reinterpret_cast<const int4*>(ei + GE)[idx];
        }
    }
    #pragma unroll
    for (int j = 0; j < 4; ++j) {
        if (ok[j]) {
            atomicAdd(&cnt[dv[j].x >> 9], 1);
            atomicAdd(&cnt[dv[j].y >> 9], 1);
            atomicAdd(&cnt[dv[j].z >> 9], 1);
            atomicAdd(&cnt[dv[j].w >> 9], 1);
        }
    }
    __syncthreads();
    if (t < NSB && cnt[t] > 0) gb[t] = atomicAdd(&sbcur[t], cnt[t]);
    __syncthreads();
    #pragma unroll
    for (int j = 0; j < 4; ++j) {
        if (ok[j]) {
            int b, r;
            b = dv[j].x >> 9; r = atomicAdd(&cur[b], 1); gdata[gb[b] + r] = ((dv[j].x & 511) << 17) | sv[j].x;
            b = dv[j].y >> 9; r = atomicAdd(&cur[b], 1); gdata[gb[b] + r] = ((dv[j].y & 511) << 17) | sv[j].y;
            b = dv[j].z >> 9; r = atomicAdd(&cur[b], 1); gdata[gb[b] + r] = ((dv[j].z & 511) << 17) | sv[j].z;
            b = dv[j].w >> 9; r = atomicAdd(&cur[b], 1); gdata[gb[b] + r] = ((dv[j].w & 511) << 17) | sv[j].w;
        }
    }
}

// ---------------- pass B: per-super-bucket counting sort -> CSR ----------------
// One block per super-bucket (512 nodes, ~16K entries, 64KB block-private window).
__global__ __launch_bounds__(256) void k_nsort(const int* __restrict__ gdata, const int* __restrict__ sbbase,
                                               int* __restrict__ csr, int* __restrict__ row_start,
                                               float* __restrict__ dinv) {
    const int sb = blockIdx.x;
    const int t = threadIdx.x;
    const int base = sbbase[sb];
    const int n = sbbase[sb + 1] - base;
    __shared__ int cnt[512], s[512], cur[512];
    cnt[t] = 0; cnt[t + 256] = 0;
    __syncthreads();
    for (int i = t; i < n; i += 256) atomicAdd(&cnt[gdata[base + i] >> 17], 1);
    __syncthreads();
    s[t] = cnt[t]; s[t + 256] = cnt[t + 256];
    __syncthreads();
    for (int off = 1; off < 512; off <<= 1) {          // Hillis-Steele over 512 with 256 thr
        int a0 = (t >= off) ? s[t - off] : 0;
        int a1 = (t + 256 >= off) ? s[t + 256 - off] : 0;
        __syncthreads();
        s[t] += a0; s[t + 256] += a1;
        __syncthreads();
    }
    #pragma unroll
    for (int h = 0; h < 2; ++h) {
        int ln = t + h * 256;
        int node = sb * 512 + ln;
        if (node < GN) {
            int excl = s[ln] - cnt[ln];
            row_start[node] = base + excl;
            dinv[node] = rsqrtf((float)(cnt[ln] + 1));
        }
        cur[ln] = 0;
    }
    __syncthreads();
    for (int i = t; i < n; i += 256) {
        int pk = gdata[base + i];
        int dl = pk >> 17;
        int slot = (s[dl] - cnt[dl]) + atomicAdd(&cur[dl], 1);
        csr[base + slot] = pk & 0x1FFFF;
    }
    if (sb == 0 && t == 0) row_start[GN] = GE;
}

// ---------------- layer 1 linear: hs1 = dinv * (x @ W1) ----------------
__global__ __launch_bounds__(256) void k_lin1(const float* __restrict__ x, const float* __restrict__ W1,
                                              const float* __restrict__ dinv, float* __restrict__ hs1) {
    __shared__ float w1t[HID * 516];             // transposed, pad 512->516 (2-way LDS = free)
    for (int i = threadIdx.x; i < F_IN * HID; i += 256) {
        int k = i >> 4, c = i & 15;
        w1t[c * 516 + k] = W1[i];
    }
    __syncthreads();
    const int g = threadIdx.x >> 4;              // row within batch (0..15)
    const int t = threadIdx.x & 15;              // k-slice lane
    for (int batch = blockIdx.x; batch < GN / 16; batch += gridDim.x) {
        const int row = batch * 16 + g;
        const float* xr = x + (size_t)row * F_IN;
        float acc[16];
        #pragma unroll
        for (int c = 0; c < 16; ++c) acc[c] = 0.f;
        #pragma unroll
        for (int j = 0; j < 8; ++j) {
            const int k = j * 64 + t * 4;
            float4 xv = *reinterpret_cast<const float4*>(xr + k);
            #pragma unroll
            for (int c = 0; c < 16; ++c) {
                float4 wv = *reinterpret_cast<const float4*>(&w1t[c * 516 + k]);
                acc[c] += xv.x * wv.x + xv.y * wv.y + xv.z * wv.z + xv.w * wv.w;
            }
        }
        #pragma unroll
        for (int m = 1, nv = 16; m < 16; m <<= 1, nv >>= 1) {
            #pragma unroll
            for (int j = 0; j < 8; ++j) {
                if (j < nv / 2) {
                    float a = acc[2 * j], bb = acc[2 * j + 1];
                    bool hi = (t & m);
                    float mine  = hi ? bb : a;
                    float other = hi ? a : bb;
                    acc[j] = mine + __shfl_xor(other, m, 64);
                }
            }
        }
        hs1[(size_t)row * HID + t] = dinv[row] * acc[0];
    }
}

// ---------------- aggregation 1: p = dinv * relu( dinv*(hs1[d]+sum hs1[s]) + b1 ) ----------------
__global__ __launch_bounds__(256) void k_agg1(const float* __restrict__ hs1, const int* __restrict__ csr,
                                              const int* __restrict__ row_start, const float* __restrict__ dinv,
                                              const float* __restrict__ b1, float* __restrict__ p) {
    int d = blockIdx.x * 16 + (threadIdx.x >> 4);   // exact: 6250*16 = 100000
    int c = threadIdx.x & 15;
    float acc = hs1[(size_t)d * HID + c];           // self-loop (already dinv[d]-scaled)
    int e0 = row_start[d], e1 = row_start[d + 1];
    int e = e0;
    for (; e + 8 <= e1; e += 8) {
        float v0 = hs1[(size_t)csr[e + 0] * HID + c];
        float v1 = hs1[(size_t)csr[e + 1] * HID + c];
        float v2 = hs1[(size_t)csr[e + 2] * HID + c];
        float v3 = hs1[(size_t)csr[e + 3] * HID + c];
        float v4 = hs1[(size_t)csr[e + 4] * HID + c];
        float v5 = hs1[(size_t)csr[e + 5] * HID + c];
        float v6 = hs1[(size_t)csr[e + 6] * HID + c];
        float v7 = hs1[(size_t)csr[e + 7] * HID + c];
        acc += ((v0 + v1) + (v2 + v3)) + ((v4 + v5) + (v6 + v7));
    }
    for (; e < e1; ++e) acc += hs1[(size_t)csr[e] * HID + c];
    float di = dinv[d];
    float v = fmaxf(di * acc + b1[c], 0.f);
    p[(size_t)d * HID + c] = di * v;                // pre-scale for layer-2 aggregation
}

// ---------------- agg2 + lin2 fused: out = (dinv*(p[d]+sum p[s])) @ W2 + b2 ----------------
__global__ __launch_bounds__(256) void k_agg2lin2(const float* __restrict__ p, const int* __restrict__ csr,
                                                  const int* __restrict__ row_start, const float* __restrict__ dinv,
                                                  const float* __restrict__ W2, const float* __restrict__ b2,
                                                  float* __restrict__ out) {
    __shared__ float w2[HID * NCLS];
    __shared__ float b2s[NCLS];
    __shared__ float qs[16][17];
    for (int i = threadIdx.x; i < HID * NCLS; i += 256) w2[i] = W2[i];
    if (threadIdx.x < NCLS) b2s[threadIdx.x] = b2[threadIdx.x];
    const int g = threadIdx.x >> 4;
    const int c = threadIdx.x & 15;
    const int d = blockIdx.x * 16 + g;
    float acc = p[(size_t)d * HID + c];
    int e0 = row_start[d], e1 = row_start[d + 1];
    int e = e0;
    for (; e + 8 <= e1; e += 8) {
        float v0 = p[(size_t)csr[e + 0] * HID + c];
        float v1 = p[(size_t)csr[e + 1] * HID + c];
        float v2 = p[(size_t)csr[e + 2] * HID + c];
        float v3 = p[(size_t)csr[e + 3] * HID + c];
        float v4 = p[(size_t)csr[e + 4] * HID + c];
        float v5 = p[(size_t)csr[e + 5] * HID + c];
        float v6 = p[(size_t)csr[e + 6] * HID + c];
        float v7 = p[(size_t)csr[e + 7] * HID + c];
        acc += ((v0 + v1) + (v2 + v3)) + ((v4 + v5) + (v6 + v7));
    }
    for (; e < e1; ++e) acc += p[(size_t)csr[e] * HID + c];
    qs[g][c] = dinv[d] * acc;
    __syncthreads();
    // lin2: lane c -> columns c, c+16, (c<8: c+32)
    float a0 = b2s[c], a1 = b2s[c + 16], a2 = (c < 8) ? b2s[c + 32] : 0.f;
    #pragma unroll
    for (int k = 0; k < 16; ++k) {
        float qk = qs[g][k];
        a0 += qk * w2[k * NCLS + c];
        a1 += qk * w2[k * NCLS + c + 16];
        if (c < 8) a2 += qk * w2[k * NCLS + c + 32];
    }
    float* orow = out + (size_t)d * NCLS;
    orow[c] = a0;
    orow[c + 16] = a1;
    if (c < 8) orow[c + 32] = a2;
}

// ---------------- launch ----------------

extern "C" void kernel_launch(void* const* d_in, const int* in_sizes, int n_in,
                              void* d_out, int out_size, void* d_ws, size_t ws_size,
                              hipStream_t stream) {
    const float* x  = (const float*)d_in[0];
    const int*   ei = (const int*)d_in[1];
    const float* W1 = (const float*)d_in[2];
    const float* b1 = (const float*)d_in[3];
    const float* W2 = (const float*)d_in[4];
    const float* b2 = (const float*)d_in[5];
    float* out = (float*)d_out;

    char* base = (char*)d_ws;
    size_t o = 0;
    auto alloc = [&](size_t bytes) { char* r = base + o; o = (o + bytes + 255) & ~(size_t)255; return r; };
    int*   sbcnt     = (int*)  alloc((size_t)NSB * 4);
    int*   sbbase    = (int*)  alloc(((size_t)NSB + 1) * 4);
    int*   sbcur     = (int*)  alloc((size_t)NSB * 4);
    int*   gdata     = (int*)  alloc((size_t)GE * 4);
    int*   csr       = (int*)  alloc((size_t)GE * 4);
    int*   row_start = (int*)  alloc(((size_t)GN + 1) * 4);
    float* dinv      = (float*)alloc((size_t)GN * 4);
    float* hs1       = (float*)alloc((size_t)GN * HID * 4);
    float* p         = (float*)alloc((size_t)GN * HID * 4);

    hipMemsetAsync(sbcnt, 0, (size_t)NSB * 4, stream);

    k_sbhist<<<512, 256, 0, stream>>>(ei + GE, sbcnt);
    k_sbscan<<<1, 256, 0, stream>>>(sbcnt, sbbase, sbcur);
    k_scat  <<<NSCB, 256, 0, stream>>>(ei, sbcur, gdata);
    k_nsort <<<NSB, 256, 0, stream>>>(gdata, sbbase, csr, row_start, dinv);

    k_lin1    <<<2048, 256, 0, stream>>>(x, W1, dinv, hs1);
    k_agg1    <<<GN / 16, 256, 0, stream>>>(hs1, csr, row_start, dinv, b1, p);
    k_agg2lin2<<<GN / 16, 256, 0, stream>>>(p, csr, row_start, dinv, W2, b2, out);
}